// Round 1
// baseline (478.539 us; speedup 1.0000x reference)
//
#include <hip/hip_runtime.h>
#include <stdint.h>

// Problem: B=32, C=256, H=W=32 (HW=1024), GROUPS=32 (8 ch/group), EPS=1e-5.
// Pipeline:
//   K0 wprep : Wt_m[d][c] = gs[c]*W[c][d]*scale (bf16), bias_m[d] = (b[d]+sum_c gb[c]*W[c][d])*scale
//              (scale = 1/16 for q — folds softmax C^-0.5, exact pow2)
//   K1 gn    : per (b,group) mean/var, write Xh[b][p][c] = (x-mu)*rsqrt(var+eps) (bf16)
//   K2 gemmNT: Qt[b][p][d], Kt[b][p][d]  (MODE0: bias per col)
//              Vc[b][c][p]               (MODE1: bias per row, batch remap)
//   K3 attn  : flash attention per batch, O[b][p][c] bf16 (reuses Xh buffer)
//   K4 gemmNT: out[b][d][p] = x + Wo^T O + bo (MODE2: fp32 + residual)

#define NB 32
#define CH 256
#define HWPX 1024

typedef __bf16 bf16x8 __attribute__((ext_vector_type(8)));
typedef float f32x4 __attribute__((ext_vector_type(4)));
typedef unsigned short u16;
typedef u16 u16x8 __attribute__((ext_vector_type(8)));

__device__ __forceinline__ u16 f2bf(float f) {
    union { float f; unsigned int u; } v; v.f = f;
    unsigned int r = v.u + 0x7FFFu + ((v.u >> 16) & 1u);
    return (u16)(r >> 16);
}
__device__ __forceinline__ bf16x8 ldb8(const u16* p) {
    return __builtin_bit_cast(bf16x8, *(const u16x8*)p);
}

// ---------------- K0: weight prep (grid = 4*256 blocks, 256 thr) ----------------
__global__ __launch_bounds__(256) void wprep(
    const float* __restrict__ Wq, const float* __restrict__ bq,
    const float* __restrict__ gqs, const float* __restrict__ gqb,
    const float* __restrict__ Wk, const float* __restrict__ bk,
    const float* __restrict__ gks, const float* __restrict__ gkb,
    const float* __restrict__ Wv, const float* __restrict__ bv,
    const float* __restrict__ gvs, const float* __restrict__ gvb,
    const float* __restrict__ Wo, const float* __restrict__ bo,
    u16* __restrict__ Wt, float* __restrict__ bias)
{
    int m = blockIdx.x >> 8;     // matrix 0..3 (q,k,v,o)
    int d = blockIdx.x & 255;    // output column of original W
    int c = threadIdx.x;         // input channel
    const float *W, *bb, *gs, *gb; float scale;
    if (m == 0)      { W = Wq; bb = bq; gs = gqs; gb = gqb; scale = 1.f/16.f; }
    else if (m == 1) { W = Wk; bb = bk; gs = gks; gb = gkb; scale = 1.f; }
    else if (m == 2) { W = Wv; bb = bv; gs = gvs; gb = gvb; scale = 1.f; }
    else             { W = Wo; bb = bo; gs = nullptr; gb = nullptr; scale = 1.f; }
    float w   = W[c * 256 + d];
    float gsc = gs ? gs[c] : 1.f;
    float gbc = gb ? gb[c] : 0.f;
    Wt[((size_t)m << 16) + d * 256 + c] = f2bf(w * gsc * scale);
    __shared__ float red[256];
    red[c] = gbc * w;
    __syncthreads();
    for (int s = 128; s > 0; s >>= 1) { if (c < s) red[c] += red[c + s]; __syncthreads(); }
    if (c == 0) bias[m * 256 + d] = (bb[d] + red[0]) * scale;
}

// ---------------- K1: groupnorm -> Xh[b][p][c] bf16 (grid = 1024, 256 thr) ------
__global__ __launch_bounds__(256) void gn_kernel(const float* __restrict__ x,
                                                 u16* __restrict__ Xh)
{
    int blk = blockIdx.x;
    int b = blk >> 5, g = blk & 31;
    const float* base = x + (size_t)(b * 256 + g * 8) * 1024;
    int t = threadIdx.x;
    float s = 0.f, s2 = 0.f;
    for (int i = 0; i < 32; i++) { float v = base[t + i * 256]; s += v; s2 += v * v; }
    __shared__ float rs[256], rq[256];
    rs[t] = s; rq[t] = s2;
    __syncthreads();
    for (int k = 128; k > 0; k >>= 1) {
        if (t < k) { rs[t] += rs[t + k]; rq[t] += rq[t + k]; }
        __syncthreads();
    }
    float mu  = rs[0] * (1.f / 8192.f);
    float var = rq[0] * (1.f / 8192.f) - mu * mu;
    float rv  = rsqrtf(var + 1e-5f);
    u16* outp = Xh + (size_t)b * (HWPX * CH) + g * 8;
    for (int it = 0; it < 4; it++) {
        int p = t + it * 256;
        u16x8 tv;
        #pragma unroll
        for (int c2 = 0; c2 < 8; c2++) tv[c2] = f2bf((base[c2 * 1024 + p] - mu) * rv);
        *(u16x8*)(outp + (size_t)p * 256) = tv;
    }
}

// ---------------- K2/K4: NT GEMM, K=256, block 64x64, 4 waves ----------------
// MODE0: C_bf16[m][256] = A[m][k] B[n][k]^T + bias[n]          (Q,K proj)
// MODE1: Vc[b][m][p]    = ... + bias[m], n=(b,p)               (V proj)
// MODE2: out[b][m][p]   = ... + bias[m] + x[b][m][p], fp32     (final proj)
template <int MODE>
__global__ __launch_bounds__(256) void gemm_nt(
    const u16* __restrict__ A, const u16* __restrict__ Bm,
    const float* __restrict__ bias,
    u16* __restrict__ Cb, float* __restrict__ Cf,
    const float* __restrict__ xres)
{
    int lane = threadIdx.x & 63;
    int wave = threadIdx.x >> 6;
    int m0 = blockIdx.y * 64 + wave * 16;
    int n0 = blockIdx.x * 64;
    int lr = lane & 15;
    int lk = (lane >> 4) * 8;
    f32x4 acc[4] = {};
    const u16* Ap = A + (size_t)(m0 + lr) * 256 + lk;
    #pragma unroll
    for (int kk = 0; kk < 8; kk++) {
        bf16x8 af = ldb8(Ap + kk * 32);
        #pragma unroll
        for (int nt = 0; nt < 4; nt++) {
            const u16* Bp = Bm + (size_t)(n0 + nt * 16 + lr) * 256 + kk * 32 + lk;
            acc[nt] = __builtin_amdgcn_mfma_f32_16x16x32_bf16(af, ldb8(Bp), acc[nt], 0, 0, 0);
        }
    }
    int rbase = m0 + ((lane >> 4) << 2);
    #pragma unroll
    for (int nt = 0; nt < 4; nt++) {
        int col = n0 + nt * 16 + lr;
        #pragma unroll
        for (int j = 0; j < 4; j++) {
            int row = rbase + j;
            float v = acc[nt][j];
            if (MODE == 0) {
                v += bias[col];
                Cb[(size_t)row * 256 + col] = f2bf(v);
            } else {
                int b = col >> 10, p = col & 1023;
                size_t off = (size_t)b * (CH * HWPX) + (size_t)row * 1024 + p;
                v += bias[row];
                if (MODE == 1) Cb[off] = f2bf(v);
                else           Cf[off] = v + xres[off];
            }
        }
    }
}

// ---------------- K3: flash attention per batch ----------------
// grid = 32*16 blocks, 256 thr (4 waves); wave owns 16 q-rows; full seq 1024.
__global__ __launch_bounds__(256, 2) void attn(
    const u16* __restrict__ Qt, const u16* __restrict__ Kt,
    const u16* __restrict__ Vc, u16* __restrict__ O)
{
    int lane = threadIdx.x & 63, wave = threadIdx.x >> 6;
    int b = blockIdx.x >> 4, qb = blockIdx.x & 15;
    const u16* Qb = Qt + (size_t)b * (HWPX * CH);
    const u16* Kb = Kt + (size_t)b * (HWPX * CH);
    const u16* Vb = Vc + (size_t)b * (CH * HWPX);
    int q0 = qb * 64 + wave * 16;
    int lr = lane & 15, hk = lane >> 4, lk = hk * 8;

    bf16x8 qf[8];
    #pragma unroll
    for (int kk = 0; kk < 8; kk++)
        qf[kk] = ldb8(Qb + (size_t)(q0 + lr) * 256 + kk * 32 + lk);

    f32x4 oa[16] = {};
    float m_run[4] = {-1e30f, -1e30f, -1e30f, -1e30f};
    float l_run[4] = {0.f, 0.f, 0.f, 0.f};

    __shared__ __align__(16) u16 P_lds[4][16 * 64];
    u16* Pw = P_lds[wave];
    const float LOG2E = 1.4426950408889634f;

    for (int r0 = 0; r0 < 1024; r0 += 64) {
        f32x4 sacc[4] = {};
        #pragma unroll
        for (int kk = 0; kk < 8; kk++) {
            #pragma unroll
            for (int nt = 0; nt < 4; nt++) {
                bf16x8 kf = ldb8(Kb + (size_t)(r0 + nt * 16 + lr) * 256 + kk * 32 + lk);
                sacc[nt] = __builtin_amdgcn_mfma_f32_16x16x32_bf16(qf[kk], kf, sacc[nt], 0, 0, 0);
            }
        }
        // online softmax (rows = (lane>>4)*4+j ; cols across lr and nt)
        float sc[4];
        float pr[4][4];
        #pragma unroll
        for (int j = 0; j < 4; j++) {
            float mx = fmaxf(fmaxf(sacc[0][j], sacc[1][j]), fmaxf(sacc[2][j], sacc[3][j]));
            #pragma unroll
            for (int d2 = 1; d2 < 16; d2 <<= 1) mx = fmaxf(mx, __shfl_xor(mx, d2));
            float mn = fmaxf(m_run[j], mx);
            sc[j] = exp2f((m_run[j] - mn) * LOG2E);
            float rsum = 0.f;
            #pragma unroll
            for (int nt = 0; nt < 4; nt++) {
                float pv = exp2f((sacc[nt][j] - mn) * LOG2E);
                pr[nt][j] = pv; rsum += pv;
            }
            #pragma unroll
            for (int d2 = 1; d2 < 16; d2 <<= 1) rsum += __shfl_xor(rsum, d2);
            l_run[j] = l_run[j] * sc[j] + rsum;
            m_run[j] = mn;
        }
        #pragma unroll
        for (int ct = 0; ct < 16; ct++) {
            f32x4 t = oa[ct];
            t[0] *= sc[0]; t[1] *= sc[1]; t[2] *= sc[2]; t[3] *= sc[3];
            oa[ct] = t;
        }
        // P -> LDS (XOR swizzle on 16B granules to kill stride-128B bank conflict)
        #pragma unroll
        for (int nt = 0; nt < 4; nt++) {
            #pragma unroll
            for (int j = 0; j < 4; j++) {
                int row = hk * 4 + j;
                int idx = (row * 64 + nt * 16 + lr) ^ ((row & 7) << 3);
                Pw[idx] = f2bf(pr[nt][j]);
            }
        }
        __syncthreads();
        #pragma unroll
        for (int ks = 0; ks < 2; ks++) {
            int ridx = (lr * 64 + ks * 32 + lk) ^ ((lr & 7) << 3);
            bf16x8 pf = ldb8(Pw + ridx);
            #pragma unroll
            for (int ct = 0; ct < 16; ct++) {
                bf16x8 vf = ldb8(Vb + (size_t)(ct * 16 + lr) * 1024 + r0 + ks * 32 + lk);
                oa[ct] = __builtin_amdgcn_mfma_f32_16x16x32_bf16(pf, vf, oa[ct], 0, 0, 0);
            }
        }
        __syncthreads();
    }
    float rinv[4];
    #pragma unroll
    for (int j = 0; j < 4; j++) rinv[j] = 1.f / l_run[j];
    u16* Ob = O + (size_t)b * (HWPX * CH);
    #pragma unroll
    for (int ct = 0; ct < 16; ct++) {
        #pragma unroll
        for (int j = 0; j < 4; j++) {
            Ob[(size_t)(q0 + hk * 4 + j) * 256 + ct * 16 + lr] = f2bf(oa[ct][j] * rinv[j]);
        }
    }
}

// ---------------- host launch ----------------
extern "C" void kernel_launch(void* const* d_in, const int* in_sizes, int n_in,
                              void* d_out, int out_size, void* d_ws, size_t ws_size,
                              hipStream_t stream)
{
    const float* x   = (const float*)d_in[0];
    const float* Wq  = (const float*)d_in[1];
    const float* bq  = (const float*)d_in[2];
    const float* Wk  = (const float*)d_in[3];
    const float* bk  = (const float*)d_in[4];
    const float* Wv  = (const float*)d_in[5];
    const float* bv  = (const float*)d_in[6];
    const float* Wo  = (const float*)d_in[7];
    const float* bo  = (const float*)d_in[8];
    const float* gqs = (const float*)d_in[9];
    const float* gqb = (const float*)d_in[10];
    const float* gks = (const float*)d_in[11];
    const float* gkb = (const float*)d_in[12];
    const float* gvs = (const float*)d_in[13];
    const float* gvb = (const float*)d_in[14];

    const size_t BIG = (size_t)NB * HWPX * CH;     // 8388608 elems
    size_t need = 4 * BIG * 2 + 4 * 65536 * 2 + 4 * 256 * 4;
    if (ws_size < need) return;

    char* w = (char*)d_ws;
    u16*  Xh   = (u16*)(w);                        // [B][p][c] ; later reused as O[b][p][c]
    u16*  Qt   = (u16*)(w + 2 * BIG);              // [B][p][d]
    u16*  Kt   = (u16*)(w + 4 * BIG);              // [B][p][d]
    u16*  Vc   = (u16*)(w + 6 * BIG);              // [B][c][p]
    u16*  Wt   = (u16*)(w + 8 * BIG);              // 4 x [d][c]
    float* bias = (float*)(w + 8 * BIG + 4 * 65536 * 2);

    wprep<<<dim3(1024), dim3(256), 0, stream>>>(Wq, bq, gqs, gqb, Wk, bk, gks, gkb,
                                                Wv, bv, gvs, gvb, Wo, bo, Wt, bias);
    gn_kernel<<<dim3(1024), dim3(256), 0, stream>>>(x, Xh);

    // Q = Xh * Wt_q^T (+bq')  -> Qt[p][d]   (already pre-scaled by 1/16)
    gemm_nt<0><<<dim3(4, 512), dim3(256), 0, stream>>>(Xh, Wt,           bias,       Qt, nullptr, nullptr);
    // K
    gemm_nt<0><<<dim3(4, 512), dim3(256), 0, stream>>>(Xh, Wt + 65536,   bias + 256, Kt, nullptr, nullptr);
    // V: Vc[b][c][p] = Wt_v * Xh^T (+bv')
    gemm_nt<1><<<dim3(512, 4), dim3(256), 0, stream>>>(Wt + 131072, Xh,  bias + 512, Vc, nullptr, nullptr);
    // attention: O written into Xh buffer (Xh dead after V projection)
    attn<<<dim3(512), dim3(256), 0, stream>>>(Qt, Kt, Vc, Xh);
    // out[b][d][p] = x + Wo^T O + bo
    gemm_nt<2><<<dim3(512, 4), dim3(256), 0, stream>>>(Wt + 196608, Xh,  bias + 768, nullptr, (float*)d_out, x);
}

// Round 2
// 181.306 us; speedup vs baseline: 2.6394x; 2.6394x over previous
//
#include <hip/hip_runtime.h>
#include <stdint.h>

// B=32, C=256, H=W=32 (HW=1024), GROUPS=32, EPS=1e-5.
// K0 wprep : Wt[d][c] = gs[c]*W[c][d]*scale (bf16); bias[d]=(b[d]+sum_c gb[c]W[c][d])*scale
//            q-scale = log2(e)/16  (folds softmax 1/sqrt(C) AND exp->exp2 domain)
// K1 gn    : Xh[b][p][c] = (x-mu)*rsqrt(var+eps) (bf16)
// K2 gemmNT: shared B-tile (64x256=32KB) staged via global_load_lds, XOR-swizzled
// K3 attn  : flash attn, KV step 32: K dbuf 2x16KB + V 16KB + P 5KB LDS,
//            2-phase pipeline (stage after barrier, drain at next __syncthreads)
// K4 gemmNT: out = x + Wo^T O + bo (fp32)

#define NB 32
#define CH 256
#define HWPX 1024

typedef __bf16 bf16x8 __attribute__((ext_vector_type(8)));
typedef float f32x4 __attribute__((ext_vector_type(4)));
typedef unsigned short u16;
typedef u16 u16x8 __attribute__((ext_vector_type(8)));

__device__ __forceinline__ u16 f2bf(float f) {
    union { float f; unsigned int u; } v; v.f = f;
    unsigned int r = v.u + 0x7FFFu + ((v.u >> 16) & 1u);
    return (u16)(r >> 16);
}
__device__ __forceinline__ bf16x8 ldb8(const u16* p) {
    return __builtin_bit_cast(bf16x8, *(const u16x8*)p);
}
__device__ __forceinline__ void gld_lds16(const u16* g, u16* l) {
    __builtin_amdgcn_global_load_lds(
        (const __attribute__((address_space(1))) void*)g,
        (__attribute__((address_space(3))) void*)l, 16, 0, 0);
}

// ---------------- K0: weight prep ----------------
__global__ __launch_bounds__(256) void wprep(
    const float* __restrict__ Wq, const float* __restrict__ bq,
    const float* __restrict__ gqs, const float* __restrict__ gqb,
    const float* __restrict__ Wk, const float* __restrict__ bk,
    const float* __restrict__ gks, const float* __restrict__ gkb,
    const float* __restrict__ Wv, const float* __restrict__ bv,
    const float* __restrict__ gvs, const float* __restrict__ gvb,
    const float* __restrict__ Wo, const float* __restrict__ bo,
    u16* __restrict__ Wt, float* __restrict__ bias)
{
    int m = blockIdx.x >> 8;
    int d = blockIdx.x & 255;
    int c = threadIdx.x;
    const float *W, *bb, *gs, *gb; float scale;
    const float QSC = 0.09016844005556021f;   // log2(e)/16
    if (m == 0)      { W = Wq; bb = bq; gs = gqs; gb = gqb; scale = QSC; }
    else if (m == 1) { W = Wk; bb = bk; gs = gks; gb = gkb; scale = 1.f; }
    else if (m == 2) { W = Wv; bb = bv; gs = gvs; gb = gvb; scale = 1.f; }
    else             { W = Wo; bb = bo; gs = nullptr; gb = nullptr; scale = 1.f; }
    float w   = W[c * 256 + d];
    float gsc = gs ? gs[c] : 1.f;
    float gbc = gb ? gb[c] : 0.f;
    Wt[((size_t)m << 16) + d * 256 + c] = f2bf(w * gsc * scale);
    __shared__ float red[256];
    red[c] = gbc * w;
    __syncthreads();
    for (int s = 128; s > 0; s >>= 1) { if (c < s) red[c] += red[c + s]; __syncthreads(); }
    if (c == 0) bias[m * 256 + d] = (bb[d] + red[0]) * scale;
}

// ---------------- K1: groupnorm ----------------
__global__ __launch_bounds__(256) void gn_kernel(const float* __restrict__ x,
                                                 u16* __restrict__ Xh)
{
    int blk = blockIdx.x;
    int b = blk >> 5, g = blk & 31;
    const float* base = x + (size_t)(b * 256 + g * 8) * 1024;
    int t = threadIdx.x;
    float s = 0.f, s2 = 0.f;
    for (int i = 0; i < 32; i++) { float v = base[t + i * 256]; s += v; s2 += v * v; }
    __shared__ float rs[256], rq[256];
    rs[t] = s; rq[t] = s2;
    __syncthreads();
    for (int k = 128; k > 0; k >>= 1) {
        if (t < k) { rs[t] += rs[t + k]; rq[t] += rq[t + k]; }
        __syncthreads();
    }
    float mu  = rs[0] * (1.f / 8192.f);
    float var = rq[0] * (1.f / 8192.f) - mu * mu;
    float rv  = rsqrtf(var + 1e-5f);
    u16* outp = Xh + (size_t)b * (HWPX * CH) + g * 8;
    for (int it = 0; it < 4; it++) {
        int p = t + it * 256;
        u16x8 tv;
        #pragma unroll
        for (int c2 = 0; c2 < 8; c2++) tv[c2] = f2bf((base[c2 * 1024 + p] - mu) * rv);
        *(u16x8*)(outp + (size_t)p * 256) = tv;
    }
}

// ---------------- K2/K4: NT GEMM, shared B-tile in LDS ----------------
// MODE0: C_bf16[m][256] = A[m][:] B[n][:]^T + bias[n]
// MODE1: Vc[b][m][p]    = ... + bias[m]   (n = b*1024+p)
// MODE2: out[b][m][p]   = ... + bias[m] + x, fp32
template <int MODE>
__global__ __launch_bounds__(256) void gemm_nt(
    const u16* __restrict__ A, const u16* __restrict__ Bm,
    const float* __restrict__ bias,
    u16* __restrict__ Cb, float* __restrict__ Cf,
    const float* __restrict__ xres)
{
    __shared__ __align__(16) u16 Bt[64 * 256];        // 32 KB, XOR-swizzled granules
    int tid = threadIdx.x;
    int lane = tid & 63, wave = tid >> 6;
    int m0 = blockIdx.y * 64 + wave * 16;
    int n0 = blockIdx.x * 64;

    // stage B-tile: rows n0..n0+63, 2048 granules of 16B. dest linear, src col ^= row&7
    #pragma unroll
    for (int i = 0; i < 8; i++) {
        int G = i * 256 + tid;
        int row = G >> 5, g = G & 31;
        const u16* src = Bm + (size_t)(n0 + row) * 256 + ((g ^ (row & 7)) << 3);
        gld_lds16(src, Bt + (size_t)(i * 256 + wave * 64) * 8);
    }

    int lr = lane & 15, hk = lane >> 4, lk = hk * 8;
    int ksw = lr & 7;
    const u16* Ap = A + (size_t)(m0 + lr) * 256 + lk;
    bf16x8 af[8];
    #pragma unroll
    for (int kk = 0; kk < 8; kk++) af[kk] = ldb8(Ap + kk * 32);

    __syncthreads();   // drains global_load_lds (vmcnt 0 before barrier)

    f32x4 acc[4] = {};
    #pragma unroll
    for (int kk = 0; kk < 8; kk++) {
        #pragma unroll
        for (int nt = 0; nt < 4; nt++) {
            int row = nt * 16 + lr;
            int g = (kk * 4 + hk) ^ ksw;
            bf16x8 bf = ldb8(Bt + (size_t)(row * 32 + g) * 8);
            acc[nt] = __builtin_amdgcn_mfma_f32_16x16x32_bf16(af[kk], bf, acc[nt], 0, 0, 0);
        }
    }
    int rbase = m0 + (hk << 2);
    #pragma unroll
    for (int nt = 0; nt < 4; nt++) {
        int col = n0 + nt * 16 + lr;
        #pragma unroll
        for (int j = 0; j < 4; j++) {
            int row = rbase + j;
            float v = acc[nt][j];
            if (MODE == 0) {
                v += bias[col];
                Cb[(size_t)row * 256 + col] = f2bf(v);
            } else {
                int b = col >> 10, p = col & 1023;
                size_t off = (size_t)b * (CH * HWPX) + (size_t)row * 1024 + p;
                v += bias[row];
                if (MODE == 1) Cb[off] = f2bf(v);
                else           Cf[off] = v + xres[off];
            }
        }
    }
}

// ---------------- K3: flash attention, staged + pipelined ----------------
// 512 blocks (XCD-swizzled), 4 waves x 16 q-rows, KV step 32, 32 steps.
__global__ __launch_bounds__(256) void attn(
    const u16* __restrict__ Qt, const u16* __restrict__ Kt,
    const u16* __restrict__ Vc, u16* __restrict__ O)
{
    __shared__ __align__(16) u16 Kbuf[2][32 * 256];   // 2 x 16 KB, row-major, col-gran ^= row&7
    __shared__ __align__(16) u16 Vbuf[256 * 32];      // 16 KB, 64B rows, gran ^= (row>>1)&3
    __shared__ __align__(16) u16 Pbuf[4][16 * 40];    // padded rows (80B), 5 KB

    int tid = threadIdx.x;
    int lane = tid & 63, wave = tid >> 6;
    int bid = blockIdx.x;
    // bijective XCD swizzle: batch b's 16 q-blocks land on one XCD (K/V 1MB -> L2-resident)
    int b  = (bid & 7) + ((bid >> 7) << 3);
    int qb = (bid >> 3) & 15;

    const u16* Qb = Qt + (size_t)b * (HWPX * CH);
    const u16* Kb = Kt + (size_t)b * (HWPX * CH);
    const u16* Vb = Vc + (size_t)b * (CH * HWPX);
    int q0 = qb * 64 + wave * 16;
    int lr = lane & 15, hk = lane >> 4, lk = hk * 8;
    int ksw = lr & 7;            // K/B-tile read swizzle (row&7 == lr&7)
    int vsw = (lr >> 1) & 3;     // V read swizzle ((row>>1)&3 == (lr>>1)&3)

    // per-lane staging source offsets (u16 elements)
    int koff[4], voff[4];
    #pragma unroll
    for (int i = 0; i < 4; i++) {
        int G = i * 256 + tid;
        int kr = G >> 5, kg = G & 31;
        koff[i] = kr * 256 + ((kg ^ (kr & 7)) << 3);
        int vr = G >> 2, vg = G & 3;
        voff[i] = vr * 1024 + ((vg ^ ((vr >> 1) & 3)) << 3);
    }

    bf16x8 qf[8];
    #pragma unroll
    for (int kk = 0; kk < 8; kk++)
        qf[kk] = ldb8(Qb + (size_t)(q0 + lr) * 256 + kk * 32 + lk);

    f32x4 oa[16] = {};
    float m_run[4] = {-1e30f, -1e30f, -1e30f, -1e30f};
    float l_run[4] = {0.f, 0.f, 0.f, 0.f};
    u16* Pw = Pbuf[wave];

    // prologue: stage K(0) into buf 0
    #pragma unroll
    for (int i = 0; i < 4; i++)
        gld_lds16(Kb + koff[i], Kbuf[0] + (size_t)(i * 256 + wave * 64) * 8);

    for (int t = 0; t < 32; ++t) {
        int kcur = t & 1;
        __syncthreads();   // B1: K(t) staged+drained; all waves done with Vbuf/P of t-1

        // stage K(t+1) and V(t) — overlap with QK+softmax, drained at B2
        if (t < 31) {
            u16* kd = Kbuf[0] + (size_t)(kcur ^ 1) * (32 * 256);
            const u16* ks = Kb + (t + 1) * (32 * 256);
            #pragma unroll
            for (int i = 0; i < 4; i++)
                gld_lds16(ks + koff[i], kd + (size_t)(i * 256 + wave * 64) * 8);
        }
        {
            const u16* vs = Vb + t * 32;
            #pragma unroll
            for (int i = 0; i < 4; i++)
                gld_lds16(vs + voff[i], Vbuf + (size_t)(i * 256 + wave * 64) * 8);
        }

        // ---- QK^T (S in log2 domain; Q pre-scaled by log2e/16) ----
        const u16* krd = Kbuf[0] + (size_t)kcur * (32 * 256);
        f32x4 sacc[2] = {};
        #pragma unroll
        for (int kk = 0; kk < 8; kk++) {
            #pragma unroll
            for (int nt = 0; nt < 2; nt++) {
                int row = nt * 16 + lr;
                int g = (kk * 4 + hk) ^ ksw;
                bf16x8 kf = ldb8(krd + (size_t)(row * 32 + g) * 8);
                sacc[nt] = __builtin_amdgcn_mfma_f32_16x16x32_bf16(qf[kk], kf, sacc[nt], 0, 0, 0);
            }
        }
        // ---- online softmax (exp2 domain) ----
        float sc[4];
        #pragma unroll
        for (int j = 0; j < 4; j++) {
            float mx = fmaxf(sacc[0][j], sacc[1][j]);
            #pragma unroll
            for (int d2 = 1; d2 < 16; d2 <<= 1) mx = fmaxf(mx, __shfl_xor(mx, d2));
            float mn = fmaxf(m_run[j], mx);
            sc[j] = exp2f(m_run[j] - mn);
            float p0 = exp2f(sacc[0][j] - mn);
            float p1 = exp2f(sacc[1][j] - mn);
            float rsum = p0 + p1;
            #pragma unroll
            for (int d2 = 1; d2 < 16; d2 <<= 1) rsum += __shfl_xor(rsum, d2);
            l_run[j] = l_run[j] * sc[j] + rsum;
            m_run[j] = mn;
            Pw[(hk * 4 + j) * 40 + lr]      = f2bf(p0);
            Pw[(hk * 4 + j) * 40 + 16 + lr] = f2bf(p1);
        }
        #pragma unroll
        for (int ct = 0; ct < 16; ct++) {
            f32x4 tacc = oa[ct];
            tacc[0] *= sc[0]; tacc[1] *= sc[1]; tacc[2] *= sc[2]; tacc[3] *= sc[3];
            oa[ct] = tacc;
        }

        __syncthreads();   // B2: V(t)+K(t+1) staged+drained; P visible; K reads done

        // ---- PV ----
        bf16x8 pf = ldb8(Pw + lr * 40 + lk);
        #pragma unroll
        for (int ct = 0; ct < 16; ct++) {
            int row = ct * 16 + lr;
            int vg = hk ^ vsw;
            bf16x8 vf = ldb8(Vbuf + (size_t)(row * 4 + vg) * 8);
            oa[ct] = __builtin_amdgcn_mfma_f32_16x16x32_bf16(pf, vf, oa[ct], 0, 0, 0);
        }
    }

    float rinv[4];
    #pragma unroll
    for (int j = 0; j < 4; j++) rinv[j] = 1.f / l_run[j];
    u16* Ob = O + (size_t)b * (HWPX * CH);
    #pragma unroll
    for (int ct = 0; ct < 16; ct++) {
        #pragma unroll
        for (int j = 0; j < 4; j++) {
            Ob[(size_t)(q0 + hk * 4 + j) * 256 + ct * 16 + lr] = f2bf(oa[ct][j] * rinv[j]);
        }
    }
}

// ---------------- host launch ----------------
extern "C" void kernel_launch(void* const* d_in, const int* in_sizes, int n_in,
                              void* d_out, int out_size, void* d_ws, size_t ws_size,
                              hipStream_t stream)
{
    const float* x   = (const float*)d_in[0];
    const float* Wq  = (const float*)d_in[1];
    const float* bq  = (const float*)d_in[2];
    const float* Wk  = (const float*)d_in[3];
    const float* bk  = (const float*)d_in[4];
    const float* Wv  = (const float*)d_in[5];
    const float* bv  = (const float*)d_in[6];
    const float* Wo  = (const float*)d_in[7];
    const float* bo  = (const float*)d_in[8];
    const float* gqs = (const float*)d_in[9];
    const float* gqb = (const float*)d_in[10];
    const float* gks = (const float*)d_in[11];
    const float* gkb = (const float*)d_in[12];
    const float* gvs = (const float*)d_in[13];
    const float* gvb = (const float*)d_in[14];

    const size_t BIG = (size_t)NB * HWPX * CH;
    size_t need = 4 * BIG * 2 + 4 * 65536 * 2 + 4 * 256 * 4;
    if (ws_size < need) return;

    char* w = (char*)d_ws;
    u16*  Xh   = (u16*)(w);                        // [B][p][c]; reused as O after V proj
    u16*  Qt   = (u16*)(w + 2 * BIG);              // [B][p][d]
    u16*  Kt   = (u16*)(w + 4 * BIG);              // [B][p][d]
    u16*  Vc   = (u16*)(w + 6 * BIG);              // [B][c][p]
    u16*  Wt   = (u16*)(w + 8 * BIG);              // 4 x [d][c]
    float* bias = (float*)(w + 8 * BIG + 4 * 65536 * 2);

    wprep<<<dim3(1024), dim3(256), 0, stream>>>(Wq, bq, gqs, gqb, Wk, bk, gks, gkb,
                                                Wv, bv, gvs, gvb, Wo, bo, Wt, bias);
    gn_kernel<<<dim3(1024), dim3(256), 0, stream>>>(x, Xh);

    gemm_nt<0><<<dim3(4, 512), dim3(256), 0, stream>>>(Xh, Wt,           bias,       Qt, nullptr, nullptr);
    gemm_nt<0><<<dim3(4, 512), dim3(256), 0, stream>>>(Xh, Wt + 65536,   bias + 256, Kt, nullptr, nullptr);
    gemm_nt<1><<<dim3(512, 4), dim3(256), 0, stream>>>(Wt + 131072, Xh,  bias + 512, Vc, nullptr, nullptr);
    attn<<<dim3(512), dim3(256), 0, stream>>>(Qt, Kt, Vc, Xh);
    gemm_nt<2><<<dim3(512, 4), dim3(256), 0, stream>>>(Wt + 196608, Xh,  bias + 768, nullptr, (float*)d_out, x);
}